// Round 2
// baseline (405.411 us; speedup 1.0000x reference)
//
#include <hip/hip_runtime.h>
#include <hip/hip_bf16.h>

#define DH 32
#define BN 64   // nodes per block in node_proj
#define GN 8    // nodes per 32-lane group

// ---------------------------------------------------------------------------
// Zero deg. Must run every call (counts accumulate; ws not re-poisoned).
// ---------------------------------------------------------------------------
__global__ __launch_bounds__(256) void zero_deg(int* __restrict__ deg, int N) {
    int i = blockIdx.x * blockDim.x + threadIdx.x;
    if (i < N) deg[i] = 0;
}

// ---------------------------------------------------------------------------
// deg[v] = number of edge endpoints touching v (counts duplicates, matches ref)
// ---------------------------------------------------------------------------
__global__ __launch_bounds__(256) void count_deg(
    const int* __restrict__ src, const int* __restrict__ dst,
    int* __restrict__ deg, int E)
{
    int e = blockIdx.x * blockDim.x + threadIdx.x;
    if (e >= E) return;
    atomicAdd(&deg[src[e]], 1);
    atomicAdd(&deg[dst[e]], 1);
}

// ---------------------------------------------------------------------------
// Exclusive scan of deg -> rowptr.  3 kernels: block scan (1024 elems/block),
// scan of block sums, add-back.
// ---------------------------------------------------------------------------
__global__ __launch_bounds__(256) void scan1(
    const int* __restrict__ deg, int* __restrict__ rowptr,
    int* __restrict__ bsum, int N)
{
    __shared__ int s[256];
    const int t = threadIdx.x;
    const int base = blockIdx.x * 1024 + t * 4;
    int v0 = (base + 0 < N) ? deg[base + 0] : 0;
    int v1 = (base + 1 < N) ? deg[base + 1] : 0;
    int v2 = (base + 2 < N) ? deg[base + 2] : 0;
    int v3 = (base + 3 < N) ? deg[base + 3] : 0;
    int tsum = v0 + v1 + v2 + v3;
    s[t] = tsum;
    __syncthreads();
    for (int off = 1; off < 256; off <<= 1) {
        int y = (t >= off) ? s[t - off] : 0;
        __syncthreads();
        s[t] += y;
        __syncthreads();
    }
    int excl = s[t] - tsum;
    if (t == 255) bsum[blockIdx.x] = s[255];
    if (base + 0 < N) rowptr[base + 0] = excl;
    if (base + 1 < N) rowptr[base + 1] = excl + v0;
    if (base + 2 < N) rowptr[base + 2] = excl + v0 + v1;
    if (base + 3 < N) rowptr[base + 3] = excl + v0 + v1 + v2;
}

__global__ __launch_bounds__(128) void scan2(int* __restrict__ bsum, int nb) {
    __shared__ int s[128];
    const int t = threadIdx.x;
    int v = (t < nb) ? bsum[t] : 0;
    s[t] = v;
    __syncthreads();
    for (int off = 1; off < 128; off <<= 1) {
        int y = (t >= off) ? s[t - off] : 0;
        __syncthreads();
        s[t] += y;
        __syncthreads();
    }
    if (t < nb) bsum[t] = s[t] - v;   // exclusive
}

__global__ __launch_bounds__(256) void scan3(
    int* __restrict__ rowptr, const int* __restrict__ bsum, int N)
{
    int i = blockIdx.x * blockDim.x + threadIdx.x;
    if (i < N) rowptr[i] += bsum[i >> 10];
}

// ---------------------------------------------------------------------------
// Scatter neighbor ids. Position via atomicAdd on rowptr itself; afterwards
// rowptr[v] = end of v's segment (start = rowptr[v] - deg[v]).
// ---------------------------------------------------------------------------
__global__ __launch_bounds__(256) void scatter(
    const int* __restrict__ src, const int* __restrict__ dst,
    int* __restrict__ rowptr, int* __restrict__ nbr, int E)
{
    int e = blockIdx.x * blockDim.x + threadIdx.x;
    if (e >= E) return;
    int s = src[e], d = dst[e];
    int p = atomicAdd(&rowptr[s], 1);
    nbr[p] = d;
    int q = atomicAdd(&rowptr[d], 1);
    nbr[q] = s;
}

// ---------------------------------------------------------------------------
// h = feat @ W_in + b_in            [N,128]@[128,32]
// u = sigmoid(h @ W_nbr + b_nbr + b_neighbor1)   [N,32]@[32,32]
// ---------------------------------------------------------------------------
__global__ __launch_bounds__(256) void node_proj(
    const float* __restrict__ feat,
    const float* __restrict__ W_in, const float* __restrict__ b_in,
    const float* __restrict__ W_nbr, const float* __restrict__ b_nbr,
    const float* __restrict__ b_n1,
    float* __restrict__ h, float* __restrict__ u, int N)
{
    __shared__ float sfeat[BN * 128];      // 32 KB
    __shared__ float sWt_in[32 * 132];     // Wt[c][k], padded stride 132
    __shared__ float sWt_nbr[32 * 36];     // Wt[c][k], padded stride 36
    __shared__ float sh[BN * 32];          // 8 KB
    __shared__ float sb_in[32], sb2[32];

    const int tid = threadIdx.x;
    const int base = blockIdx.x * BN;

    for (int i = tid; i < 128 * 32; i += 256) {
        int k = i >> 5, c = i & 31;
        sWt_in[c * 132 + k] = W_in[i];
    }
    for (int i = tid; i < 32 * 32; i += 256) {
        int k = i >> 5, c = i & 31;
        sWt_nbr[c * 36 + k] = W_nbr[i];
    }
    if (tid < 32) { sb_in[tid] = b_in[tid]; sb2[tid] = b_nbr[tid] + b_n1[tid]; }

    for (int i = tid; i < BN * 128 / 4; i += 256) {
        int row = i >> 5;
        int node = base + row;
        float4 v = make_float4(0.f, 0.f, 0.f, 0.f);
        if (node < N) v = *(const float4*)&feat[(size_t)node * 128 + (size_t)(i & 31) * 4];
        *(float4*)&sfeat[(size_t)i * 4] = v;
    }
    __syncthreads();

    const int g = tid >> 5, c = tid & 31;

    float acc[GN];
#pragma unroll
    for (int m = 0; m < GN; ++m) acc[m] = sb_in[c];

    const float* wcol = &sWt_in[c * 132];
    for (int kk = 0; kk < 128; kk += 4) {
        float4 w = *(const float4*)&wcol[kk];
#pragma unroll
        for (int m = 0; m < GN; ++m) {
            float4 f = *(const float4*)&sfeat[(g * GN + m) * 128 + kk];
            acc[m] += f.x * w.x + f.y * w.y + f.z * w.z + f.w * w.w;
        }
    }

#pragma unroll
    for (int m = 0; m < GN; ++m) {
        int node = base + g * GN + m;
        sh[(g * GN + m) * 32 + c] = acc[m];
        if (node < N) h[(size_t)node * 32 + c] = acc[m];
    }
    __syncthreads();

    float acc2[GN];
#pragma unroll
    for (int m = 0; m < GN; ++m) acc2[m] = sb2[c];

    const float* wcol2 = &sWt_nbr[c * 36];
    for (int kk = 0; kk < 32; kk += 4) {
        float4 w = *(const float4*)&wcol2[kk];
#pragma unroll
        for (int m = 0; m < GN; ++m) {
            float4 hf = *(const float4*)&sh[(g * GN + m) * 32 + kk];
            acc2[m] += hf.x * w.x + hf.y * w.y + hf.z * w.z + hf.w * w.w;
        }
    }

#pragma unroll
    for (int m = 0; m < GN; ++m) {
        int node = base + g * GN + m;
        if (node < N) {
            float s = 1.0f / (1.0f + __expf(-acc2[m]));
            u[(size_t)node * 32 + c] = s;
        }
    }
}

// ---------------------------------------------------------------------------
// agg[v] = max over neighbors of u[nbr]  (0 if deg<=1, folding the mask here).
// 32 lanes per node (lane = channel); neighbor list reads broadcast; u-row
// reads are 128B coalesced and L2/L3-resident.
// ---------------------------------------------------------------------------
__global__ __launch_bounds__(256) void gather_max(
    const int* __restrict__ rowptr, const int* __restrict__ deg,
    const int* __restrict__ nbr, const float* __restrict__ u,
    float* __restrict__ agg, int N)
{
    const int g = threadIdx.x >> 5, c = threadIdx.x & 31;
    const int v = blockIdx.x * 8 + g;
    if (v >= N) return;
    const int n = deg[v];
    const int base = rowptr[v] - n;    // rowptr holds segment END after scatter
    float m = 0.f;
    if (n > 1) {
        int j = 0;
        for (; j + 4 <= n; j += 4) {
            int n0 = nbr[base + j], n1 = nbr[base + j + 1];
            int n2 = nbr[base + j + 2], n3 = nbr[base + j + 3];
            float a = u[(size_t)n0 * DH + c];
            float b = u[(size_t)n1 * DH + c];
            float x = u[(size_t)n2 * DH + c];
            float y = u[(size_t)n3 * DH + c];
            m = fmaxf(fmaxf(m, fmaxf(a, b)), fmaxf(x, y));
        }
        for (; j < n; ++j) m = fmaxf(m, u[(size_t)nbr[base + j] * DH + c]);
    }
    agg[(size_t)v * DH + c] = m;
}

// ---------------------------------------------------------------------------
// out = concat(h, agg) @ W_ffnn + b_ffnn    [N,64]@[64,32]  (mask pre-applied)
// ---------------------------------------------------------------------------
__global__ __launch_bounds__(256) void finalize(
    const float* __restrict__ h, const float* __restrict__ agg,
    const float* __restrict__ W_ffnn, const float* __restrict__ b_ffnn,
    float* __restrict__ out, int N)
{
    __shared__ float sWt[32 * 68];
    __shared__ float sx[8][68];
    __shared__ float sb[32];

    const int tid = threadIdx.x;
    for (int i = tid; i < 64 * 32; i += 256) {
        int k = i >> 5, c = i & 31;
        sWt[c * 68 + k] = W_ffnn[i];
    }
    if (tid < 32) sb[tid] = b_ffnn[tid];

    const int g = tid >> 5, c = tid & 31;
    const int node = blockIdx.x * 8 + g;

    float hv = 0.f, av = 0.f;
    if (node < N) {
        hv = h[(size_t)node * DH + c];
        av = agg[(size_t)node * DH + c];
    }
    sx[g][c] = hv;
    sx[g][32 + c] = av;
    __syncthreads();

    float acc = sb[c];
    const float* wcol = &sWt[c * 68];
#pragma unroll
    for (int kk = 0; kk < 64; kk += 4) {
        float4 w = *(const float4*)&wcol[kk];
        float4 x = *(const float4*)&sx[g][kk];
        acc += x.x * w.x + x.y * w.y + x.z * w.z + x.w * w.w;
    }
    if (node < N) out[(size_t)node * DH + c] = acc;
}

// ---------------------------------------------------------------------------
extern "C" void kernel_launch(void* const* d_in, const int* in_sizes, int n_in,
                              void* d_out, int out_size, void* d_ws, size_t ws_size,
                              hipStream_t stream)
{
    const float* feat   = (const float*)d_in[0];
    const int*   src    = (const int*)d_in[1];
    const int*   dst    = (const int*)d_in[2];
    const float* W_in   = (const float*)d_in[3];
    const float* b_in   = (const float*)d_in[4];
    const float* W_nbr  = (const float*)d_in[5];
    const float* b_nbr  = (const float*)d_in[6];
    const float* b_n1   = (const float*)d_in[7];
    const float* W_ffnn = (const float*)d_in[8];
    const float* b_ffnn = (const float*)d_in[9];
    float* out = (float*)d_out;

    const int N = in_sizes[0] / 128;
    const int E = in_sizes[1];

    // u aliases d_out: node_proj writes it, gather_max consumes it, then
    // finalize overwrites d_out (same-stream ordering makes this safe).
    float* u   = out;
    float* h   = (float*)d_ws;                  // N*32 f32
    float* agg = h + (size_t)N * DH;            // N*32 f32
    int*   deg = (int*)(agg + (size_t)N * DH);  // N
    int*   rowptr = deg + N;                    // N
    int*   bsum   = rowptr + N;                 // 128
    int*   nbr    = bsum + 128;                 // 2E

    const int NB = (N + 1023) >> 10;            // blocks in scan1 (<=128)

    zero_deg<<<(N + 255) / 256, 256, 0, stream>>>(deg, N);
    count_deg<<<(E + 255) / 256, 256, 0, stream>>>(src, dst, deg, E);
    scan1<<<NB, 256, 0, stream>>>(deg, rowptr, bsum, N);
    scan2<<<1, 128, 0, stream>>>(bsum, NB);
    scan3<<<(N + 255) / 256, 256, 0, stream>>>(rowptr, bsum, N);
    scatter<<<(E + 255) / 256, 256, 0, stream>>>(src, dst, rowptr, nbr, E);
    node_proj<<<(N + BN - 1) / BN, 256, 0, stream>>>(feat, W_in, b_in, W_nbr, b_nbr,
                                                     b_n1, h, u, N);
    gather_max<<<(N + 7) / 8, 256, 0, stream>>>(rowptr, deg, nbr, u, agg, N);
    finalize<<<(N + 7) / 8, 256, 0, stream>>>(h, agg, W_ffnn, b_ffnn, out, N);
}